// Round 1
// baseline (13306.316 us; speedup 1.0000x reference)
//
#include <hip/hip_runtime.h>
#include <hip/hip_bf16.h>
#include <cstdint>

#define S_ 512
#define B_ 32
#define E_ 512
#define H_ 256
#define C_ 16

__device__ __forceinline__ float bf2f(unsigned short u) {
    return __uint_as_float(((unsigned int)u) << 16);
}
__device__ __forceinline__ unsigned short f2bf(float f) {
    unsigned int u = __float_as_uint(f);
    unsigned int r = (u + 0x7FFFu + ((u >> 16) & 1u)) >> 16;
    return (unsigned short)r;
}
__device__ __forceinline__ float sigf(float x) { return 1.f / (1.f + __expf(-x)); }
__device__ __forceinline__ float tanhf_fast(float x) {
    float e = __expf(-2.f * fabsf(x));
    float r = (1.f - e) / (1.f + e);
    return x >= 0.f ? r : -r;
}

// ---------------- embedding gather: X[s*32+b][0:512] = emb[x[b][s]] ----------------
__global__ __launch_bounds__(128) void embed_gather(
    const int* __restrict__ x, const float* __restrict__ emb, float* __restrict__ X)
{
    int row = blockIdx.x;           // s*32 + b
    int s = row >> 5, b = row & 31;
    int idx = x[b * S_ + s];
    const float4* src = (const float4*)(emb + (size_t)idx * E_);
    float4* dst = (float4*)(X + (size_t)row * E_);
    dst[threadIdx.x] = src[threadIdx.x];
}

// ---------------- generic fp32 GEMM: C[M,N] = A[M,K] @ W[N,K]^T + b1 + b2 ----------------
// 64x64 tile, 256 threads, 4x4 per thread, BK=16.
template<int STORE_BF16>
__global__ __launch_bounds__(256) void gemm_wT(
    const float* __restrict__ A, const float* __restrict__ W,
    const float* __restrict__ b1, const float* __restrict__ b2,
    void* __restrict__ Cout, int M, int N, int K)
{
    __shared__ float As[16][68];
    __shared__ float Ws[16][68];
    int tid = threadIdx.x;
    int m0 = blockIdx.x * 64, n0 = blockIdx.y * 64;
    int lr = tid >> 2;            // 0..63 tile row
    int lc = (tid & 3) * 4;       // k sub-offset
    int ty = tid >> 4, tx = tid & 15;
    float acc[4][4] = {};
    for (int k0 = 0; k0 < K; k0 += 16) {
        float4 av = *(const float4*)(A + (size_t)(m0 + lr) * K + k0 + lc);
        float4 wv = *(const float4*)(W + (size_t)(n0 + lr) * K + k0 + lc);
        __syncthreads();
        As[lc + 0][lr] = av.x; As[lc + 1][lr] = av.y; As[lc + 2][lr] = av.z; As[lc + 3][lr] = av.w;
        Ws[lc + 0][lr] = wv.x; Ws[lc + 1][lr] = wv.y; Ws[lc + 2][lr] = wv.z; Ws[lc + 3][lr] = wv.w;
        __syncthreads();
        #pragma unroll
        for (int kk = 0; kk < 16; ++kk) {
            float4 a4 = *(const float4*)&As[kk][ty * 4];
            float4 b4 = *(const float4*)&Ws[kk][tx * 4];
            acc[0][0] += a4.x * b4.x; acc[0][1] += a4.x * b4.y; acc[0][2] += a4.x * b4.z; acc[0][3] += a4.x * b4.w;
            acc[1][0] += a4.y * b4.x; acc[1][1] += a4.y * b4.y; acc[1][2] += a4.y * b4.z; acc[1][3] += a4.y * b4.w;
            acc[2][0] += a4.z * b4.x; acc[2][1] += a4.z * b4.y; acc[2][2] += a4.z * b4.z; acc[2][3] += a4.z * b4.w;
            acc[3][0] += a4.w * b4.x; acc[3][1] += a4.w * b4.y; acc[3][2] += a4.w * b4.z; acc[3][3] += a4.w * b4.w;
        }
    }
    #pragma unroll
    for (int j = 0; j < 4; ++j) {
        int n = n0 + tx * 4 + j;
        float bb = (b1 ? b1[n] : 0.f) + (b2 ? b2[n] : 0.f);
        #pragma unroll
        for (int i = 0; i < 4; ++i) {
            float v = acc[i][j] + bb;
            size_t off = (size_t)(m0 + ty * 4 + i) * N + n;
            if (STORE_BF16) ((unsigned short*)Cout)[off] = f2bf(v);
            else            ((float*)Cout)[off] = v;
        }
    }
}

// ---------------- whh transpose: whh_l[2][1024][256] -> WT[2][256][1024] (f32) ----------------
__global__ __launch_bounds__(256) void whh_transpose(
    const float* __restrict__ whh_l, float* __restrict__ WT)
{
    int i = blockIdx.x * 256 + threadIdx.x;   // [d][k][n] over 2*262144
    int d = i >> 18;
    int rem = i & 262143;
    int k = rem >> 10;
    int n = rem & 1023;
    WT[i] = whh_l[d * 262144 + n * 256 + k];
}

// ---------------- LSTM recurrence: 32 blocks = 2 dirs x 16 batch-pairs ----------------
// Zx: [S][B][1024] bf16 (x@Wih^T + bih + bhh precomputed). WT: [2][256][1024] f32.
// Hout: [S][B][512] f32, this dir writes cols d*256..d*256+255.
__global__ __launch_bounds__(256) void lstm_rec(
    const unsigned short* __restrict__ Zf, const unsigned short* __restrict__ Zb,
    const float* __restrict__ WT, float* __restrict__ Hout)
{
    int bi = blockIdx.x;
    int d = bi >> 4;
    int b0 = (bi & 15) * 2;
    const unsigned short* Z = d ? Zb : Zf;
    const float* wt = WT + d * 262144;
    __shared__ float2 hbuf[256];        // h for both batches, per k
    __shared__ float zbuf[2][1024];
    int tid = threadIdx.x;
    hbuf[tid] = make_float2(0.f, 0.f);
    float c0 = 0.f, c1 = 0.f;
    __syncthreads();
    for (int tt = 0; tt < S_; ++tt) {
        int t = d ? (S_ - 1 - tt) : tt;
        const unsigned short* zx = Z + ((size_t)t * B_ + b0) * 1024 + tid * 4;
        ushort4 z0 = *(const ushort4*)zx;
        ushort4 z1 = *(const ushort4*)(zx + 1024);
        float a0[4] = { bf2f(z0.x), bf2f(z0.y), bf2f(z0.z), bf2f(z0.w) };
        float a1[4] = { bf2f(z1.x), bf2f(z1.y), bf2f(z1.z), bf2f(z1.w) };
        const float* wp = wt + tid * 4;
        #pragma unroll 4
        for (int k = 0; k < 256; ++k) {
            float2 h2 = hbuf[k];
            float4 w = *(const float4*)(wp + (size_t)k * 1024);
            a0[0] += h2.x * w.x; a0[1] += h2.x * w.y; a0[2] += h2.x * w.z; a0[3] += h2.x * w.w;
            a1[0] += h2.y * w.x; a1[1] += h2.y * w.y; a1[2] += h2.y * w.z; a1[3] += h2.y * w.w;
        }
        #pragma unroll
        for (int c2 = 0; c2 < 4; ++c2) { zbuf[0][tid * 4 + c2] = a0[c2]; zbuf[1][tid * 4 + c2] = a1[c2]; }
        __syncthreads();
        // gates: i,f,g,o at offsets 0,256,512,768; this thread owns h-dim = tid
        float i0 = zbuf[0][tid], f0 = zbuf[0][256 + tid], g0 = zbuf[0][512 + tid], o0 = zbuf[0][768 + tid];
        float i1 = zbuf[1][tid], f1 = zbuf[1][256 + tid], g1 = zbuf[1][512 + tid], o1 = zbuf[1][768 + tid];
        c0 = sigf(f0) * c0 + sigf(i0) * tanhf_fast(g0);
        float h0 = sigf(o0) * tanhf_fast(c0);
        c1 = sigf(f1) * c1 + sigf(i1) * tanhf_fast(g1);
        float h1 = sigf(o1) * tanhf_fast(c1);
        hbuf[tid] = make_float2(h0, h1);
        size_t ho = ((size_t)t * B_ + b0) * 512 + d * 256 + tid;
        Hout[ho] = h0;
        Hout[ho + 512] = h1;
        __syncthreads();
    }
}

// ---------------- fused attention (per head h, per "batch" s; attention over l,m = B axis) ----------------
// qkv: [s*32+l][1536] bf16. out: [s*32+l][512] f32 at cols h*256..h*256+255.
__global__ __launch_bounds__(256) void attn_fused(
    const unsigned short* __restrict__ qkv, float* __restrict__ outp)
{
    int s = blockIdx.x & 511;
    int h = blockIdx.x >> 9;
    __shared__ float qs[32][260];
    __shared__ float ks[32][260];
    __shared__ float vs[32][260];
    __shared__ float sc[32][36];
    int tid = threadIdx.x;
    for (int it = 0; it < 32; ++it) {
        const unsigned short* base = qkv + ((size_t)s * 32 + it) * 1536 + h * 256 + tid;
        qs[it][tid] = bf2f(base[0]);
        ks[it][tid] = bf2f(base[512]);
        vs[it][tid] = bf2f(base[1024]);
    }
    __syncthreads();
    // scores: thread t -> l = t>>3, m-block of 4
    int l = tid >> 3, m0 = (tid & 7) * 4;
    float a0 = 0, a1 = 0, a2 = 0, a3 = 0;
    for (int dd = 0; dd < 256; dd += 4) {
        float4 q4 = *(const float4*)&qs[l][dd];
        float4 k0v = *(const float4*)&ks[m0 + 0][dd];
        float4 k1v = *(const float4*)&ks[m0 + 1][dd];
        float4 k2v = *(const float4*)&ks[m0 + 2][dd];
        float4 k3v = *(const float4*)&ks[m0 + 3][dd];
        a0 += q4.x * k0v.x + q4.y * k0v.y + q4.z * k0v.z + q4.w * k0v.w;
        a1 += q4.x * k1v.x + q4.y * k1v.y + q4.z * k1v.z + q4.w * k1v.w;
        a2 += q4.x * k2v.x + q4.y * k2v.y + q4.z * k2v.z + q4.w * k2v.w;
        a3 += q4.x * k3v.x + q4.y * k3v.y + q4.z * k3v.z + q4.w * k3v.w;
    }
    sc[l][m0 + 0] = a0 * 0.0625f;
    sc[l][m0 + 1] = a1 * 0.0625f;
    sc[l][m0 + 2] = a2 * 0.0625f;
    sc[l][m0 + 3] = a3 * 0.0625f;
    __syncthreads();
    if (tid < 32) {
        float mx = -1e30f;
        for (int m = 0; m < 32; ++m) mx = fmaxf(mx, sc[tid][m]);
        float pr[32]; float sm = 0.f;
        for (int m = 0; m < 32; ++m) { pr[m] = __expf(sc[tid][m] - mx); sm += pr[m]; }
        float inv = 1.f / sm;
        for (int m = 0; m < 32; ++m) sc[tid][m] = pr[m] * inv;
    }
    __syncthreads();
    // out[l][d] = sum_m attn[l][m] * v[m][d]; thread t -> l = t>>3, d-block of 32
    int l2 = tid >> 3, d0 = (tid & 7) * 32;
    float o[32] = {};
    for (int m = 0; m < 32; ++m) {
        float aw = sc[l2][m];
        #pragma unroll
        for (int dd = 0; dd < 32; dd += 4) {
            float4 v4 = *(const float4*)&vs[m][d0 + dd];
            o[dd] += aw * v4.x; o[dd + 1] += aw * v4.y; o[dd + 2] += aw * v4.z; o[dd + 3] += aw * v4.w;
        }
    }
    float* ob = outp + ((size_t)s * 32 + l2) * 512 + h * 256 + d0;
    #pragma unroll
    for (int dd = 0; dd < 32; dd += 4)
        *(float4*)(ob + dd) = make_float4(o[dd], o[dd + 1], o[dd + 2], o[dd + 3]);
}

// ---------------- fc: logits[b][s][c] = A[s*32+b][:512] . fcw[c][:512] + fcb[c] ----------------
__global__ __launch_bounds__(256) void fc_logits(
    const float* __restrict__ A, const float* __restrict__ fcw, const float* __restrict__ fcb,
    float* __restrict__ outp)
{
    __shared__ float wsm[16][516];
    int tid = threadIdx.x;
    for (int idx = tid; idx < 8192; idx += 256) wsm[idx >> 9][idx & 511] = fcw[idx];
    __syncthreads();
    int r = blockIdx.x * 16 + (tid >> 4);
    int c = tid & 15;
    const float* ar = A + (size_t)r * 512;
    float acc = 0.f;
    for (int k = 0; k < 512; k += 4) {
        float4 a4 = *(const float4*)(ar + k);
        float4 w4 = *(const float4*)&wsm[c][k];
        acc += a4.x * w4.x + a4.y * w4.y + a4.z * w4.z + a4.w * w4.w;
    }
    int s = r >> 5, b = r & 31;
    outp[(size_t)b * 8192 + s * 16 + c] = acc + fcb[c];
}

// ---------------- CRF: per-b block; numerator (parallel) + forward algorithm (sequential t) ----------------
__global__ __launch_bounds__(256) void crf_forward(
    const float* __restrict__ em, const int* __restrict__ labels,
    const float* __restrict__ cs, const float* __restrict__ ce, const float* __restrict__ ct,
    float* __restrict__ res)
{
    int b = blockIdx.x;
    int tid = threadIdx.x;
    int jj = tid >> 4, ii = tid & 15;
    __shared__ float trans[16][17];
    __shared__ float alpha[2][16];
    __shared__ float red[256];
    trans[tid >> 4][tid & 15] = ct[tid & 255];
    const float* emb_ = em + (size_t)b * 8192;   // [t][c], t-major for this b
    const int* tg = labels + b * 512;
    float part = 0.f;
    for (int t = tid; t < 512; t += 256) {
        int cur = tg[t];
        part += emb_[t * 16 + cur] + (t == 0 ? cs[cur] : ct[tg[t - 1] * 16 + cur]);
    }
    red[tid] = part;
    if (tid < 16) alpha[0][tid] = cs[tid] + emb_[tid];
    __syncthreads();
    for (int off = 128; off > 0; off >>= 1) {
        if (tid < off) red[tid] += red[tid + off];
        __syncthreads();
    }
    for (int t = 1; t < 512; ++t) {
        int p = t & 1;
        float v = alpha[p ^ 1][ii] + trans[ii][jj];
        float mx = v;
        mx = fmaxf(mx, __shfl_xor(mx, 1));
        mx = fmaxf(mx, __shfl_xor(mx, 2));
        mx = fmaxf(mx, __shfl_xor(mx, 4));
        mx = fmaxf(mx, __shfl_xor(mx, 8));
        float e = __expf(v - mx);
        e += __shfl_xor(e, 1); e += __shfl_xor(e, 2); e += __shfl_xor(e, 4); e += __shfl_xor(e, 8);
        if (ii == 0) alpha[p][jj] = mx + __logf(e) + emb_[t * 16 + jj];
        __syncthreads();
    }
    if (tid == 0) {
        float mx = -1e30f;
        for (int c2 = 0; c2 < 16; ++c2) mx = fmaxf(mx, alpha[1][c2] + ce[c2]);
        float sm = 0.f;
        for (int c2 = 0; c2 < 16; ++c2) sm += __expf(alpha[1][c2] + ce[c2] - mx);
        float logZ = mx + __logf(sm);
        float score = red[0] + ce[tg[511]];
        res[b] = logZ - score;    // contribution to nll
    }
}

__global__ void crf_final(const float* __restrict__ res, float* __restrict__ nll)
{
    if (threadIdx.x == 0) {
        float s2 = 0.f;
        for (int b = 0; b < 32; ++b) s2 += res[b];
        nll[0] = s2;
    }
}

extern "C" void kernel_launch(void* const* d_in, const int* in_sizes, int n_in,
                              void* d_out, int out_size, void* d_ws, size_t ws_size,
                              hipStream_t stream)
{
    const int* x      = (const int*)d_in[0];
    const int* labels = (const int*)d_in[1];
    const float* emb  = (const float*)d_in[2];
    const float* wih  = (const float*)d_in[3];
    const float* whh  = (const float*)d_in[4];
    const float* bih  = (const float*)d_in[5];
    const float* bhh  = (const float*)d_in[6];
    const float* inw  = (const float*)d_in[7];
    const float* inb  = (const float*)d_in[8];
    const float* opw  = (const float*)d_in[9];
    const float* opb  = (const float*)d_in[10];
    const float* fcw  = (const float*)d_in[11];
    const float* fcb  = (const float*)d_in[12];
    const float* cs   = (const float*)d_in[13];
    const float* ce   = (const float*)d_in[14];
    const float* ct   = (const float*)d_in[15];
    float* out = (float*)d_out;

    char* ws = (char*)d_ws;
    float* bufX           = (float*)(ws + 0);                    // 33.5 MB  [S][B][512] f32
    float* bufH           = (float*)(ws + (1ull << 25));         // 33.5 MB  [S][B][512] f32
    unsigned short* bufZf = (unsigned short*)(ws + (2ull << 25)); // 33.5 MB [S][B][1024] bf16 (also qkv)
    unsigned short* bufZb = (unsigned short*)(ws + (3ull << 25)); // 33.5 MB
    float* bufWT          = (float*)(ws + (4ull << 25));         // 2 MB [2][256][1024] f32
    float* res            = (float*)(ws + (4ull << 25) + (1ull << 21)); // 128 B

    // 1) embedding gather -> bufX [S][B][512]
    embed_gather<<<16384, 128, 0, stream>>>(x, emb, bufX);

    // 2) two BiLSTM layers
    for (int l = 0; l < 2; ++l) {
        const float* Xin = l ? bufH : bufX;
        float* Ho        = l ? bufX : bufH;
        whh_transpose<<<2048, 256, 0, stream>>>(whh + (size_t)l * 2 * 262144, bufWT);
        for (int dd = 0; dd < 2; ++dd) {
            gemm_wT<1><<<dim3(256, 16), 256, 0, stream>>>(
                Xin, wih + (size_t)(l * 2 + dd) * 524288,
                bih + (l * 2 + dd) * 1024, bhh + (l * 2 + dd) * 1024,
                dd ? (void*)bufZb : (void*)bufZf, 16384, 1024, 512);
        }
        lstm_rec<<<32, 256, 0, stream>>>(bufZf, bufZb, bufWT, Ho);
    }
    // final BiLSTM output is in bufX

    // 3) MHA: qkv = h @ in_proj^T + b  (bf16, into Zf/Zb region: 50.3 MB < 67 MB)
    gemm_wT<1><<<dim3(256, 24), 256, 0, stream>>>(bufX, inw, inb, nullptr, (void*)bufZf, 16384, 1536, 512);
    attn_fused<<<1024, 256, 0, stream>>>(bufZf, bufH);
    gemm_wT<0><<<dim3(256, 8), 256, 0, stream>>>(bufH, opw, opb, nullptr, (void*)bufX, 16384, 512, 512);

    // 4) logits -> d_out[0 .. 262143] as [B][S][C]
    fc_logits<<<1024, 256, 0, stream>>>(bufX, fcw, fcb, out);

    // 5) CRF nll -> d_out[262144]
    crf_forward<<<32, 256, 0, stream>>>(out, labels, cs, ce, ct, res);
    crf_final<<<1, 64, 0, stream>>>(res, out + 262144);

    (void)in_sizes; (void)n_in; (void)out_size; (void)ws_size;
}

// Round 2
// 6997.256 us; speedup vs baseline: 1.9016x; 1.9016x over previous
//
#include <hip/hip_runtime.h>
#include <hip/hip_bf16.h>
#include <cstdint>

#define S_ 512
#define B_ 32
#define E_ 512
#define H_ 256
#define C_ 16

typedef float f32x4_t __attribute__((ext_vector_type(4)));
typedef __bf16 bf16x8_t __attribute__((ext_vector_type(8)));

__device__ __forceinline__ float bf2f(unsigned short u) {
    return __uint_as_float(((unsigned int)u) << 16);
}
__device__ __forceinline__ unsigned short f2bf(float f) {
    unsigned int u = __float_as_uint(f);
    unsigned int r = (u + 0x7FFFu + ((u >> 16) & 1u)) >> 16;
    return (unsigned short)r;
}
__device__ __forceinline__ float sigf(float x) { return 1.f / (1.f + __expf(-x)); }
__device__ __forceinline__ float tanhf_fast(float x) {
    float e = __expf(-2.f * fabsf(x));
    float r = (1.f - e) / (1.f + e);
    return x >= 0.f ? r : -r;
}

// ---------------- embedding gather: X[s*32+b][0:512] = emb[x[b][s]] ----------------
__global__ __launch_bounds__(128) void embed_gather(
    const int* __restrict__ x, const float* __restrict__ emb, float* __restrict__ X)
{
    int row = blockIdx.x;           // s*32 + b
    int s = row >> 5, b = row & 31;
    int idx = x[b * S_ + s];
    const float4* src = (const float4*)(emb + (size_t)idx * E_);
    float4* dst = (float4*)(X + (size_t)row * E_);
    dst[threadIdx.x] = src[threadIdx.x];
}

// ---------------- generic fp32 GEMM: C[M,N] = A[M,K] @ W[N,K]^T + b1 + b2 ----------------
template<int STORE_BF16>
__global__ __launch_bounds__(256) void gemm_wT(
    const float* __restrict__ A, const float* __restrict__ W,
    const float* __restrict__ b1, const float* __restrict__ b2,
    void* __restrict__ Cout, int M, int N, int K)
{
    __shared__ float As[16][68];
    __shared__ float Ws[16][68];
    int tid = threadIdx.x;
    int m0 = blockIdx.x * 64, n0 = blockIdx.y * 64;
    int lr = tid >> 2;
    int lc = (tid & 3) * 4;
    int ty = tid >> 4, tx = tid & 15;
    float acc[4][4] = {};
    for (int k0 = 0; k0 < K; k0 += 16) {
        float4 av = *(const float4*)(A + (size_t)(m0 + lr) * K + k0 + lc);
        float4 wv = *(const float4*)(W + (size_t)(n0 + lr) * K + k0 + lc);
        __syncthreads();
        As[lc + 0][lr] = av.x; As[lc + 1][lr] = av.y; As[lc + 2][lr] = av.z; As[lc + 3][lr] = av.w;
        Ws[lc + 0][lr] = wv.x; Ws[lc + 1][lr] = wv.y; Ws[lc + 2][lr] = wv.z; Ws[lc + 3][lr] = wv.w;
        __syncthreads();
        #pragma unroll
        for (int kk = 0; kk < 16; ++kk) {
            float4 a4 = *(const float4*)&As[kk][ty * 4];
            float4 b4 = *(const float4*)&Ws[kk][tx * 4];
            acc[0][0] += a4.x * b4.x; acc[0][1] += a4.x * b4.y; acc[0][2] += a4.x * b4.z; acc[0][3] += a4.x * b4.w;
            acc[1][0] += a4.y * b4.x; acc[1][1] += a4.y * b4.y; acc[1][2] += a4.y * b4.z; acc[1][3] += a4.y * b4.w;
            acc[2][0] += a4.z * b4.x; acc[2][1] += a4.z * b4.y; acc[2][2] += a4.z * b4.z; acc[2][3] += a4.z * b4.w;
            acc[3][0] += a4.w * b4.x; acc[3][1] += a4.w * b4.y; acc[3][2] += a4.w * b4.z; acc[3][3] += a4.w * b4.w;
        }
    }
    #pragma unroll
    for (int j = 0; j < 4; ++j) {
        int n = n0 + tx * 4 + j;
        float bb = (b1 ? b1[n] : 0.f) + (b2 ? b2[n] : 0.f);
        #pragma unroll
        for (int i = 0; i < 4; ++i) {
            float v = acc[i][j] + bb;
            size_t off = (size_t)(m0 + ty * 4 + i) * N + n;
            if (STORE_BF16) ((unsigned short*)Cout)[off] = f2bf(v);
            else            ((float*)Cout)[off] = v;
        }
    }
}

// ---------------- zero scratch (flags + h exchange buffer) ----------------
__global__ __launch_bounds__(256) void zero_ws(unsigned int* __restrict__ p, int n)
{
    int i = blockIdx.x * 256 + threadIdx.x;
    if (i < n) p[i] = 0u;
}

// ---------------- LSTM recurrence, MFMA + LDS-resident weights ----------------
// Grid: 8 blocks = 2 dirs x 4 unit-slices (64 units each). Block: 256 thr (4 waves).
// Wave w handles gate w. LDS: Wslice [4][64][256] bf16 swizzled (128KB) +
// 16KB region shared between h_lds [32][256] bf16 (swizzled) and zbuf [4][16][64] f32.
// h exchanged via hglob (device-scope atomics), one flag per (dir, step).
__global__ __launch_bounds__(256) void lstm_rec_mfma(
    const unsigned short* __restrict__ Zf,
    const unsigned short* __restrict__ Zb,
    const float* __restrict__ whh_l,   // [2][1024][256] f32 (this layer)
    unsigned int* __restrict__ hglob,  // [2][4096] u32 = [2][32][256] bf16, pre-zeroed
    unsigned int* __restrict__ flags,  // [2][512], pre-zeroed
    float* __restrict__ Hout)          // [S][B][512] f32
{
    __shared__ __align__(16) char lds[147456];
    const int tid  = threadIdx.x;
    const int d    = blockIdx.x >> 2;
    const int p    = blockIdx.x & 3;
    const int u0   = p * 64;
    const int wv   = tid >> 6;
    const int lane = tid & 63;
    const unsigned short* Z = d ? Zb : Zf;
    unsigned int* hg = hglob + d * 4096;
    unsigned int* fl = flags + d * 512;

    // ---- one-time: load weight slice to LDS (bf16, XOR-swizzled rows) ----
    {
        int rloc = tid >> 2;        // 0..63
        int q = tid & 3;
        for (int rr = 0; rr < 256; rr += 64) {
            int r = rr + rloc;      // 0..255 = g*64 + u
            int g = r >> 6, u = r & 63;
            const float* src = whh_l + ((size_t)d * 1024 + (size_t)g * 256 + u0 + u) * 256;
            #pragma unroll
            for (int i = 0; i < 16; ++i) {
                int c4 = (i * 4 + q) * 4;
                float4 w4 = *(const float4*)(src + c4);
                ushort4 b4;
                b4.x = f2bf(w4.x); b4.y = f2bf(w4.y);
                b4.z = f2bf(w4.z); b4.w = f2bf(w4.w);
                int byt = (((g * 64 + u) * 256 + c4) * 2) ^ ((u & 7) << 4);
                *(ushort4*)(lds + byt) = b4;
            }
        }
    }

    char* hz = lds + 131072;            // h_lds / zbuf shared region (16KB)
    float* zbp = (float*)hz;            // zbuf view: [4 gates][16 b][64 u] f32
    const char* wbase = lds + (size_t)wv * 64 * 256 * 2;

    float cA[4] = {0.f, 0.f, 0.f, 0.f};
    float cB[4] = {0.f, 0.f, 0.f, 0.f};
    const int ub = tid >> 4;            // update-phase batch (0..15)
    const int uu = (tid & 15) * 4;      // unit offset within slice
    const int mrow = lane & 15;
    const int kgrp = (lane >> 4) * 8;

    __syncthreads();

    for (int tt = 0; tt < 512; ++tt) {
        const int t = d ? (511 - tt) : tt;

        // prefetch Zx (consumed in update phases; latency hidden under MFMA)
        const unsigned short* zx1p = Z + ((size_t)t * 32 + ub) * 1024 + u0 + uu;
        ushort4 zx1[4], zx2[4];
        #pragma unroll
        for (int g = 0; g < 4; ++g) {
            zx1[g] = *(const ushort4*)(zx1p + g * 256);
            zx2[g] = *(const ushort4*)(zx1p + 16 * 1024 + g * 256);
        }

        // wait for all 4 slices of previous step's h
        if (tt > 0) {
            if (tid == 0) {
                while (__hip_atomic_load(fl + (tt - 1), __ATOMIC_ACQUIRE,
                                         __HIP_MEMORY_SCOPE_AGENT) < 4u) { }
            }
            __syncthreads();
        }

        // stage h -> LDS (device-scope loads bypass stale L1/L2; zeros at tt==0)
        #pragma unroll
        for (int j = 0; j < 4; ++j) {
            int lin = j * 1024 + tid * 4;
            int b = lin >> 7, kp = lin & 127;
            unsigned int h0 = __hip_atomic_load(hg + lin + 0, __ATOMIC_RELAXED, __HIP_MEMORY_SCOPE_AGENT);
            unsigned int h1 = __hip_atomic_load(hg + lin + 1, __ATOMIC_RELAXED, __HIP_MEMORY_SCOPE_AGENT);
            unsigned int h2 = __hip_atomic_load(hg + lin + 2, __ATOMIC_RELAXED, __HIP_MEMORY_SCOPE_AGENT);
            unsigned int h3 = __hip_atomic_load(hg + lin + 3, __ATOMIC_RELAXED, __HIP_MEMORY_SCOPE_AGENT);
            int byt = ((b * 256 + kp * 2) * 2) ^ ((b & 7) << 4);
            uint4 v; v.x = h0; v.y = h1; v.z = h2; v.w = h3;
            *(uint4*)(hz + byt) = v;
        }
        __syncthreads();

        // MFMA K-loop: z[b][wv*... ] = h @ Wslice
        f32x4_t acc0[4] = {{0.f,0.f,0.f,0.f},{0.f,0.f,0.f,0.f},{0.f,0.f,0.f,0.f},{0.f,0.f,0.f,0.f}};
        f32x4_t acc1[4] = {{0.f,0.f,0.f,0.f},{0.f,0.f,0.f,0.f},{0.f,0.f,0.f,0.f},{0.f,0.f,0.f,0.f}};
        #pragma unroll
        for (int kb = 0; kb < 8; ++kb) {
            int k0 = kb * 32 + kgrp;
            bf16x8_t a0 = *(const bf16x8_t*)(hz + ((( mrow       * 256 + k0) * 2) ^ ((mrow & 7) << 4)));
            bf16x8_t a1 = *(const bf16x8_t*)(hz + ((((mrow + 16) * 256 + k0) * 2) ^ ((mrow & 7) << 4)));
            #pragma unroll
            for (int ni = 0; ni < 4; ++ni) {
                int u = ni * 16 + mrow;
                bf16x8_t bfr = *(const bf16x8_t*)(wbase + (((u * 256 + k0) * 2) ^ ((u & 7) << 4)));
                acc0[ni] = __builtin_amdgcn_mfma_f32_16x16x32_bf16(a0, bfr, acc0[ni], 0, 0, 0);
                acc1[ni] = __builtin_amdgcn_mfma_f32_16x16x32_bf16(a1, bfr, acc1[ni], 0, 0, 0);
            }
        }
        __syncthreads();   // all waves done reading h_lds; region becomes zbuf

        // ---- phase 1: batches 0..15 ----
        #pragma unroll
        for (int ni = 0; ni < 4; ++ni)
            #pragma unroll
            for (int r = 0; r < 4; ++r)
                zbp[(wv * 16 + ((lane >> 4) * 4 + r)) * 64 + ni * 16 + mrow] = acc0[ni][r];
        __syncthreads();
        {
            float4 zi4 = *(float4*)&zbp[( 0 + ub) * 64 + uu];
            float4 zf4 = *(float4*)&zbp[(16 + ub) * 64 + uu];
            float4 zg4 = *(float4*)&zbp[(32 + ub) * 64 + uu];
            float4 zo4 = *(float4*)&zbp[(48 + ub) * 64 + uu];
            float* zip = (float*)&zi4; float* zfp = (float*)&zf4;
            float* zgp = (float*)&zg4; float* zop = (float*)&zo4;
            float hh[4];
            #pragma unroll
            for (int j2 = 0; j2 < 4; ++j2) {
                float iv = sigf(zip[j2] + bf2f(((unsigned short*)&zx1[0])[j2]));
                float fv = sigf(zfp[j2] + bf2f(((unsigned short*)&zx1[1])[j2]));
                float gv = tanhf_fast(zgp[j2] + bf2f(((unsigned short*)&zx1[2])[j2]));
                float ov = sigf(zop[j2] + bf2f(((unsigned short*)&zx1[3])[j2]));
                cA[j2] = fv * cA[j2] + iv * gv;
                hh[j2] = ov * tanhf_fast(cA[j2]);
            }
            *(float4*)(Hout + ((size_t)t * 32 + ub) * 512 + d * 256 + u0 + uu)
                = make_float4(hh[0], hh[1], hh[2], hh[3]);
            unsigned int p0 = ((unsigned int)f2bf(hh[1]) << 16) | f2bf(hh[0]);
            unsigned int p1 = ((unsigned int)f2bf(hh[3]) << 16) | f2bf(hh[2]);
            int hi = ub * 128 + (u0 + uu) / 2;
            __hip_atomic_store(hg + hi,     p0, __ATOMIC_RELAXED, __HIP_MEMORY_SCOPE_AGENT);
            __hip_atomic_store(hg + hi + 1, p1, __ATOMIC_RELAXED, __HIP_MEMORY_SCOPE_AGENT);
        }
        __syncthreads();

        // ---- phase 2: batches 16..31 ----
        #pragma unroll
        for (int ni = 0; ni < 4; ++ni)
            #pragma unroll
            for (int r = 0; r < 4; ++r)
                zbp[(wv * 16 + ((lane >> 4) * 4 + r)) * 64 + ni * 16 + mrow] = acc1[ni][r];
        __syncthreads();
        {
            float4 zi4 = *(float4*)&zbp[( 0 + ub) * 64 + uu];
            float4 zf4 = *(float4*)&zbp[(16 + ub) * 64 + uu];
            float4 zg4 = *(float4*)&zbp[(32 + ub) * 64 + uu];
            float4 zo4 = *(float4*)&zbp[(48 + ub) * 64 + uu];
            float* zip = (float*)&zi4; float* zfp = (float*)&zf4;
            float* zgp = (float*)&zg4; float* zop = (float*)&zo4;
            float hh[4];
            #pragma unroll
            for (int j2 = 0; j2 < 4; ++j2) {
                float iv = sigf(zip[j2] + bf2f(((unsigned short*)&zx2[0])[j2]));
                float fv = sigf(zfp[j2] + bf2f(((unsigned short*)&zx2[1])[j2]));
                float gv = tanhf_fast(zgp[j2] + bf2f(((unsigned short*)&zx2[2])[j2]));
                float ov = sigf(zop[j2] + bf2f(((unsigned short*)&zx2[3])[j2]));
                cB[j2] = fv * cB[j2] + iv * gv;
                hh[j2] = ov * tanhf_fast(cB[j2]);
            }
            int b2 = ub + 16;
            *(float4*)(Hout + ((size_t)t * 32 + b2) * 512 + d * 256 + u0 + uu)
                = make_float4(hh[0], hh[1], hh[2], hh[3]);
            unsigned int p0 = ((unsigned int)f2bf(hh[1]) << 16) | f2bf(hh[0]);
            unsigned int p1 = ((unsigned int)f2bf(hh[3]) << 16) | f2bf(hh[2]);
            int hi = b2 * 128 + (u0 + uu) / 2;
            __hip_atomic_store(hg + hi,     p0, __ATOMIC_RELAXED, __HIP_MEMORY_SCOPE_AGENT);
            __hip_atomic_store(hg + hi + 1, p1, __ATOMIC_RELAXED, __HIP_MEMORY_SCOPE_AGENT);
        }
        __syncthreads();   // all h stores complete (vmcnt drained by barrier)

        if (tid == 0)
            __hip_atomic_fetch_add(fl + tt, 1u, __ATOMIC_RELEASE, __HIP_MEMORY_SCOPE_AGENT);
    }
}

// ---------------- fused attention (per head h, per "batch" s; attention over B axis) ----------------
__global__ __launch_bounds__(256) void attn_fused(
    const unsigned short* __restrict__ qkv, float* __restrict__ outp)
{
    int s = blockIdx.x & 511;
    int h = blockIdx.x >> 9;
    __shared__ float qs[32][260];
    __shared__ float ks[32][260];
    __shared__ float vs[32][260];
    __shared__ float sc[32][36];
    int tid = threadIdx.x;
    for (int it = 0; it < 32; ++it) {
        const unsigned short* base = qkv + ((size_t)s * 32 + it) * 1536 + h * 256 + tid;
        qs[it][tid] = bf2f(base[0]);
        ks[it][tid] = bf2f(base[512]);
        vs[it][tid] = bf2f(base[1024]);
    }
    __syncthreads();
    int l = tid >> 3, m0 = (tid & 7) * 4;
    float a0 = 0, a1 = 0, a2 = 0, a3 = 0;
    for (int dd = 0; dd < 256; dd += 4) {
        float4 q4 = *(const float4*)&qs[l][dd];
        float4 k0v = *(const float4*)&ks[m0 + 0][dd];
        float4 k1v = *(const float4*)&ks[m0 + 1][dd];
        float4 k2v = *(const float4*)&ks[m0 + 2][dd];
        float4 k3v = *(const float4*)&ks[m0 + 3][dd];
        a0 += q4.x * k0v.x + q4.y * k0v.y + q4.z * k0v.z + q4.w * k0v.w;
        a1 += q4.x * k1v.x + q4.y * k1v.y + q4.z * k1v.z + q4.w * k1v.w;
        a2 += q4.x * k2v.x + q4.y * k2v.y + q4.z * k2v.z + q4.w * k2v.w;
        a3 += q4.x * k3v.x + q4.y * k3v.y + q4.z * k3v.z + q4.w * k3v.w;
    }
    sc[l][m0 + 0] = a0 * 0.0625f;
    sc[l][m0 + 1] = a1 * 0.0625f;
    sc[l][m0 + 2] = a2 * 0.0625f;
    sc[l][m0 + 3] = a3 * 0.0625f;
    __syncthreads();
    if (tid < 32) {
        float mx = -1e30f;
        for (int m = 0; m < 32; ++m) mx = fmaxf(mx, sc[tid][m]);
        float pr[32]; float sm = 0.f;
        for (int m = 0; m < 32; ++m) { pr[m] = __expf(sc[tid][m] - mx); sm += pr[m]; }
        float inv = 1.f / sm;
        for (int m = 0; m < 32; ++m) sc[tid][m] = pr[m] * inv;
    }
    __syncthreads();
    int l2 = tid >> 3, d0 = (tid & 7) * 32;
    float o[32] = {};
    for (int m = 0; m < 32; ++m) {
        float aw = sc[l2][m];
        #pragma unroll
        for (int dd = 0; dd < 32; dd += 4) {
            float4 v4 = *(const float4*)&vs[m][d0 + dd];
            o[dd] += aw * v4.x; o[dd + 1] += aw * v4.y; o[dd + 2] += aw * v4.z; o[dd + 3] += aw * v4.w;
        }
    }
    float* ob = outp + ((size_t)s * 32 + l2) * 512 + h * 256 + d0;
    #pragma unroll
    for (int dd = 0; dd < 32; dd += 4)
        *(float4*)(ob + dd) = make_float4(o[dd], o[dd + 1], o[dd + 2], o[dd + 3]);
}

// ---------------- fc logits ----------------
__global__ __launch_bounds__(256) void fc_logits(
    const float* __restrict__ A, const float* __restrict__ fcw, const float* __restrict__ fcb,
    float* __restrict__ outp)
{
    __shared__ float wsm[16][516];
    int tid = threadIdx.x;
    for (int idx = tid; idx < 8192; idx += 256) wsm[idx >> 9][idx & 511] = fcw[idx];
    __syncthreads();
    int r = blockIdx.x * 16 + (tid >> 4);
    int c = tid & 15;
    const float* ar = A + (size_t)r * 512;
    float acc = 0.f;
    for (int k = 0; k < 512; k += 4) {
        float4 a4 = *(const float4*)(ar + k);
        float4 w4 = *(const float4*)&wsm[c][k];
        acc += a4.x * w4.x + a4.y * w4.y + a4.z * w4.z + a4.w * w4.w;
    }
    int s = r >> 5, b = r & 31;
    outp[(size_t)b * 8192 + s * 16 + c] = acc + fcb[c];
}

// ---------------- CRF ----------------
__global__ __launch_bounds__(256) void crf_forward(
    const float* __restrict__ em, const int* __restrict__ labels,
    const float* __restrict__ cs, const float* __restrict__ ce, const float* __restrict__ ct,
    float* __restrict__ res)
{
    int b = blockIdx.x;
    int tid = threadIdx.x;
    int jj = tid >> 4, ii = tid & 15;
    __shared__ float trans[16][17];
    __shared__ float alpha[2][16];
    __shared__ float red[256];
    trans[tid >> 4][tid & 15] = ct[tid & 255];
    const float* emb_ = em + (size_t)b * 8192;
    const int* tg = labels + b * 512;
    float part = 0.f;
    for (int t = tid; t < 512; t += 256) {
        int cur = tg[t];
        part += emb_[t * 16 + cur] + (t == 0 ? cs[cur] : ct[tg[t - 1] * 16 + cur]);
    }
    red[tid] = part;
    if (tid < 16) alpha[0][tid] = cs[tid] + emb_[tid];
    __syncthreads();
    for (int off = 128; off > 0; off >>= 1) {
        if (tid < off) red[tid] += red[tid + off];
        __syncthreads();
    }
    for (int t = 1; t < 512; ++t) {
        int p = t & 1;
        float v = alpha[p ^ 1][ii] + trans[ii][jj];
        float mx = v;
        mx = fmaxf(mx, __shfl_xor(mx, 1));
        mx = fmaxf(mx, __shfl_xor(mx, 2));
        mx = fmaxf(mx, __shfl_xor(mx, 4));
        mx = fmaxf(mx, __shfl_xor(mx, 8));
        float e = __expf(v - mx);
        e += __shfl_xor(e, 1); e += __shfl_xor(e, 2); e += __shfl_xor(e, 4); e += __shfl_xor(e, 8);
        if (ii == 0) alpha[p][jj] = mx + __logf(e) + emb_[t * 16 + jj];
        __syncthreads();
    }
    if (tid == 0) {
        float mx = -1e30f;
        for (int c2 = 0; c2 < 16; ++c2) mx = fmaxf(mx, alpha[1][c2] + ce[c2]);
        float sm = 0.f;
        for (int c2 = 0; c2 < 16; ++c2) sm += __expf(alpha[1][c2] + ce[c2] - mx);
        float logZ = mx + __logf(sm);
        float score = red[0] + ce[tg[511]];
        res[b] = logZ - score;
    }
}

__global__ void crf_final(const float* __restrict__ res, float* __restrict__ nll)
{
    if (threadIdx.x == 0) {
        float s2 = 0.f;
        for (int b = 0; b < 32; ++b) s2 += res[b];
        nll[0] = s2;
    }
}

extern "C" void kernel_launch(void* const* d_in, const int* in_sizes, int n_in,
                              void* d_out, int out_size, void* d_ws, size_t ws_size,
                              hipStream_t stream)
{
    const int* x      = (const int*)d_in[0];
    const int* labels = (const int*)d_in[1];
    const float* emb  = (const float*)d_in[2];
    const float* wih  = (const float*)d_in[3];
    const float* whh  = (const float*)d_in[4];
    const float* bih  = (const float*)d_in[5];
    const float* bhh  = (const float*)d_in[6];
    const float* inw  = (const float*)d_in[7];
    const float* inb  = (const float*)d_in[8];
    const float* opw  = (const float*)d_in[9];
    const float* opb  = (const float*)d_in[10];
    const float* fcw  = (const float*)d_in[11];
    const float* fcb  = (const float*)d_in[12];
    const float* cs   = (const float*)d_in[13];
    const float* ce   = (const float*)d_in[14];
    const float* ct   = (const float*)d_in[15];
    float* out = (float*)d_out;

    char* ws = (char*)d_ws;
    float* bufX           = (float*)(ws + 0);                     // [S][B][512] f32
    float* bufH           = (float*)(ws + (1ull << 25));          // [S][B][512] f32
    unsigned short* bufZf = (unsigned short*)(ws + (2ull << 25)); // [S][B][1024] bf16 / qkv
    unsigned short* bufZb = (unsigned short*)(ws + (3ull << 25));
    unsigned int* hgf     = (unsigned int*)(ws + (4ull << 25));   // hg 8192 + flags 1024 u32
    float* res            = (float*)(ws + (4ull << 25) + 40960);

    // 1) embedding gather
    embed_gather<<<16384, 128, 0, stream>>>(x, emb, bufX);

    // 2) two BiLSTM layers
    for (int l = 0; l < 2; ++l) {
        const float* Xin = l ? bufH : bufX;
        float* Ho        = l ? bufX : bufH;
        for (int dd = 0; dd < 2; ++dd) {
            gemm_wT<1><<<dim3(256, 16), 256, 0, stream>>>(
                Xin, wih + (size_t)(l * 2 + dd) * 524288,
                bih + (l * 2 + dd) * 1024, bhh + (l * 2 + dd) * 1024,
                dd ? (void*)bufZb : (void*)bufZf, 16384, 1024, 512);
        }
        zero_ws<<<36, 256, 0, stream>>>(hgf, 9216);
        lstm_rec_mfma<<<8, 256, 0, stream>>>(
            bufZf, bufZb, whh + (size_t)l * 524288,
            hgf, hgf + 8192, Ho);
    }

    // 3) MHA
    gemm_wT<1><<<dim3(256, 24), 256, 0, stream>>>(bufX, inw, inb, nullptr, (void*)bufZf, 16384, 1536, 512);
    attn_fused<<<1024, 256, 0, stream>>>(bufZf, bufH);
    gemm_wT<0><<<dim3(256, 8), 256, 0, stream>>>(bufH, opw, opb, nullptr, (void*)bufX, 16384, 512, 512);

    // 4) logits
    fc_logits<<<1024, 256, 0, stream>>>(bufX, fcw, fcb, out);

    // 5) CRF
    crf_forward<<<32, 256, 0, stream>>>(out, labels, cs, ce, ct, res);
    crf_final<<<1, 64, 0, stream>>>(res, out + 262144);

    (void)in_sizes; (void)n_in; (void)out_size; (void)ws_size;
}

// Round 3
// 5167.318 us; speedup vs baseline: 2.5751x; 1.3541x over previous
//
#include <hip/hip_runtime.h>
#include <hip/hip_bf16.h>
#include <cstdint>

#define S_ 512
#define B_ 32
#define E_ 512
#define H_ 256
#define C_ 16

typedef float f32x4_t __attribute__((ext_vector_type(4)));
typedef __bf16 bf16x8_t __attribute__((ext_vector_type(8)));

__device__ __forceinline__ float bf2f(unsigned short u) {
    return __uint_as_float(((unsigned int)u) << 16);
}
__device__ __forceinline__ unsigned short f2bf(float f) {
    unsigned int u = __float_as_uint(f);
    unsigned int r = (u + 0x7FFFu + ((u >> 16) & 1u)) >> 16;
    return (unsigned short)r;
}
__device__ __forceinline__ float sigf(float x) { return 1.f / (1.f + __expf(-x)); }
__device__ __forceinline__ float tanhf_fast(float x) {
    float e = __expf(-2.f * fabsf(x));
    float r = (1.f - e) / (1.f + e);
    return x >= 0.f ? r : -r;
}

// ---------------- embedding gather -> bf16 X[s*32+b][0:512] ----------------
__global__ __launch_bounds__(128) void embed_gather(
    const int* __restrict__ x, const float* __restrict__ emb, unsigned short* __restrict__ X)
{
    int row = blockIdx.x;           // s*32 + b
    int s = row >> 5, b = row & 31;
    int idx = x[b * S_ + s];
    float4 v = ((const float4*)(emb + (size_t)idx * E_))[threadIdx.x];
    ushort4 o; o.x = f2bf(v.x); o.y = f2bf(v.y); o.z = f2bf(v.z); o.w = f2bf(v.w);
    ((ushort4*)(X + (size_t)row * E_))[threadIdx.x] = o;
}

// ---------------- f32 -> bf16 converter (n multiple of 4) ----------------
__global__ __launch_bounds__(256) void conv_f2b(
    const float* __restrict__ src, unsigned short* __restrict__ dst, int n)
{
    int i = (blockIdx.x * 256 + threadIdx.x) * 4;
    if (i < n) {
        float4 v = *(const float4*)(src + i);
        ushort4 o; o.x = f2bf(v.x); o.y = f2bf(v.y); o.z = f2bf(v.z); o.w = f2bf(v.w);
        *(ushort4*)(dst + i) = o;
    }
}

// ---------------- zero scratch ----------------
__global__ __launch_bounds__(256) void zero_ws(unsigned int* __restrict__ p, int n)
{
    int i = blockIdx.x * 256 + threadIdx.x;
    if (i < n) p[i] = 0u;
}

// ---------------- bf16 MFMA GEMM: C[M,N] = A[M,K] @ W[N,K]^T (+b1+b2) ----------------
// 64x64 tile, 256 thr (4 waves), BK=64. Wave w owns rows w*16..w*16+15.
template<int STORE_BF16>
__global__ __launch_bounds__(256) void gemm_bf16(
    const unsigned short* __restrict__ A, const unsigned short* __restrict__ W,
    const float* __restrict__ b1, const float* __restrict__ b2,
    void* __restrict__ Cout, int M, int N, int K)
{
    __shared__ __align__(16) char lds[16384];   // A-tile 8K + W-tile 8K, swizzled
    char* asb = lds;
    char* wsb = lds + 8192;
    const int tid = threadIdx.x;
    const int m0 = blockIdx.x * 64, n0 = blockIdx.y * 64;
    const int w = tid >> 6, L = tid & 63;
    const int sr = tid >> 2, sq = tid & 3;
    const int mrow = L & 15, kg = (L >> 4) * 8;
    f32x4_t acc[4];
    #pragma unroll
    for (int ni = 0; ni < 4; ++ni) acc[ni] = f32x4_t{0.f, 0.f, 0.f, 0.f};

    for (int k0 = 0; k0 < K; k0 += 64) {
        uint4 av1 = *(const uint4*)(A + (size_t)(m0 + sr) * K + k0 + sq * 16);
        uint4 av2 = *(const uint4*)(A + (size_t)(m0 + sr) * K + k0 + sq * 16 + 8);
        uint4 wv1 = *(const uint4*)(W + (size_t)(n0 + sr) * K + k0 + sq * 16);
        uint4 wv2 = *(const uint4*)(W + (size_t)(n0 + sr) * K + k0 + sq * 16 + 8);
        __syncthreads();
        int sw = (sr & 7) << 4;
        *(uint4*)(asb + ((sr * 128 + sq * 32) ^ sw))      = av1;
        *(uint4*)(asb + ((sr * 128 + sq * 32 + 16) ^ sw)) = av2;
        *(uint4*)(wsb + ((sr * 128 + sq * 32) ^ sw))      = wv1;
        *(uint4*)(wsb + ((sr * 128 + sq * 32 + 16) ^ sw)) = wv2;
        __syncthreads();
        #pragma unroll
        for (int kb = 0; kb < 2; ++kb) {
            int kl = kb * 32 + kg;
            int ar = w * 16 + mrow;
            bf16x8_t a = *(const bf16x8_t*)(asb + ((ar * 128 + kl * 2) ^ ((ar & 7) << 4)));
            #pragma unroll
            for (int ni = 0; ni < 4; ++ni) {
                int nr = ni * 16 + mrow;
                bf16x8_t b = *(const bf16x8_t*)(wsb + ((nr * 128 + kl * 2) ^ ((nr & 7) << 4)));
                acc[ni] = __builtin_amdgcn_mfma_f32_16x16x32_bf16(a, b, acc[ni], 0, 0, 0);
            }
        }
    }
    #pragma unroll
    for (int ni = 0; ni < 4; ++ni) {
        int n = n0 + ni * 16 + mrow;
        float bb = (b1 ? b1[n] : 0.f) + (b2 ? b2[n] : 0.f);
        #pragma unroll
        for (int r = 0; r < 4; ++r) {
            int m = m0 + w * 16 + (L >> 4) * 4 + r;
            float v = acc[ni][r] + bb;
            size_t off = (size_t)m * N + n;
            if (STORE_BF16) ((unsigned short*)Cout)[off] = f2bf(v);
            else            ((float*)Cout)[off] = v;
        }
    }
}

// ---------------- LSTM recurrence: 8 blocks = 2 dir x 4 unit-slices, MFMA ----------------
// Per block: 256 thr (4 waves). Wave w owns units [p*64 + w*16, +16) across all 4 gates.
// LDS: weights [256 n][256 k] bf16 swizzled (128KB) + h [32 b][256 k] bf16 swizzled (16KB).
// hg double-buffered by step parity; per-producer monotone flags; all atomics RELAXED
// (ordering via barrier vmcnt drain; sc1 ops are IF-coherent).
__global__ __launch_bounds__(256) void lstm_rec_mfma(
    const unsigned short* __restrict__ Zf,
    const unsigned short* __restrict__ Zb,
    const float* __restrict__ whh_l,    // [2][1024][256] f32
    unsigned int* __restrict__ hglob,   // [2 dir][2 par][32 b][128] u32, pre-zeroed
    unsigned int* __restrict__ flags,   // [2 dir][4], pre-zeroed
    unsigned short* __restrict__ Hb)    // [16384][512] bf16
{
    __shared__ __align__(16) char lds[147456];
    const int tid = threadIdx.x;
    const int d = blockIdx.x >> 2;
    const int p = blockIdx.x & 3;
    const int w = tid >> 6;
    const int L = tid & 63;
    const unsigned short* Z = d ? Zb : Zf;
    unsigned int* hgd = hglob + d * 8192;
    unsigned int* fld = flags + d * 4;

    // one-time: weight slice f32 -> bf16 -> LDS (rows n = g*64+u, swizzled)
    {
        int rloc = tid >> 2, q = tid & 3;
        for (int rr = 0; rr < 256; rr += 64) {
            int r = rr + rloc;
            int g = r >> 6, u = r & 63;
            const float* src = whh_l + ((size_t)d * 1024 + g * 256 + p * 64 + u) * 256;
            #pragma unroll
            for (int i = 0; i < 16; ++i) {
                int c4 = (i * 4 + q) * 4;
                float4 w4 = *(const float4*)(src + c4);
                ushort4 b4;
                b4.x = f2bf(w4.x); b4.y = f2bf(w4.y); b4.z = f2bf(w4.z); b4.w = f2bf(w4.w);
                int byt = ((r * 256 + c4) * 2) ^ ((r & 7) << 4);
                *(ushort4*)(lds + byt) = b4;
            }
        }
    }
    char* hz = lds + 131072;
    const int sb = tid >> 3, sj = tid & 7;     // staging/pack role
    // zero own h region (state -1)
    {
        int byt = (sb * 512 + p * 128 + sj * 16) ^ ((sb & 7) << 4);
        uint4 zz; zz.x = 0; zz.y = 0; zz.z = 0; zz.w = 0;
        *(uint4*)(hz + byt) = zz;
    }
    float cst[8] = {0.f, 0.f, 0.f, 0.f, 0.f, 0.f, 0.f, 0.f};
    const int mrow = L & 15;
    const int kg = (L >> 4) * 8;
    const int ug = p * 64 + w * 16 + mrow;     // global unit index
    __syncthreads();

    for (int tt = 0; tt < 512; ++tt) {
        const int t = d ? (511 - tt) : tt;

        // prefetch Zx for this lane's 8 (b,u) pairs x 4 gates
        unsigned short zxv[4][8];
        #pragma unroll
        for (int g = 0; g < 4; ++g)
            #pragma unroll
            for (int j = 0; j < 8; ++j) {
                int b = (j >> 2) * 16 + (L >> 4) * 4 + (j & 3);
                zxv[g][j] = Z[((size_t)t * 32 + b) * 1024 + g * 256 + ug];
            }

        f32x4_t acc[4][2];
        #pragma unroll
        for (int g = 0; g < 4; ++g) {
            acc[g][0] = f32x4_t{0.f, 0.f, 0.f, 0.f};
            acc[g][1] = f32x4_t{0.f, 0.f, 0.f, 0.f};
        }

        // ---- MFMA over own k-slice (kb = 2p, 2p+1) ----
        #pragma unroll
        for (int kk = 0; kk < 2; ++kk) {
            int k0 = (2 * p + kk) * 32 + kg;
            bf16x8_t a0 = *(const bf16x8_t*)(hz + ((mrow * 512 + k0 * 2) ^ ((mrow & 7) << 4)));
            bf16x8_t a1 = *(const bf16x8_t*)(hz + (((mrow + 16) * 512 + k0 * 2) ^ ((mrow & 7) << 4)));
            #pragma unroll
            for (int g = 0; g < 4; ++g) {
                int n = g * 64 + w * 16 + mrow;
                bf16x8_t bf = *(const bf16x8_t*)(lds + ((n * 512 + k0 * 2) ^ ((n & 7) << 4)));
                acc[g][0] = __builtin_amdgcn_mfma_f32_16x16x32_bf16(a0, bf, acc[g][0], 0, 0, 0);
                acc[g][1] = __builtin_amdgcn_mfma_f32_16x16x32_bf16(a1, bf, acc[g][1], 0, 0, 0);
            }
        }

        // ---- poll peer flags (all threads; relaxed) ----
        if (tt > 0) {
            #pragma unroll
            for (int qq = 1; qq < 4; ++qq) {
                int q = (p + qq) & 3;
                while (__hip_atomic_load(fld + q, __ATOMIC_RELAXED, __HIP_MEMORY_SCOPE_AGENT)
                       < (unsigned)tt) { }
            }
        }
        // ---- stage 3 peer h slices (state tt-1, parity (tt+1)&1) ----
        {
            const unsigned int* hgp = hgd + ((tt + 1) & 1) * 4096;
            #pragma unroll
            for (int qq = 1; qq < 4; ++qq) {
                int q = (p + qq) & 3;
                const unsigned int* sp = hgp + sb * 128 + q * 32 + sj * 4;
                unsigned int v0 = __hip_atomic_load(sp + 0, __ATOMIC_RELAXED, __HIP_MEMORY_SCOPE_AGENT);
                unsigned int v1 = __hip_atomic_load(sp + 1, __ATOMIC_RELAXED, __HIP_MEMORY_SCOPE_AGENT);
                unsigned int v2 = __hip_atomic_load(sp + 2, __ATOMIC_RELAXED, __HIP_MEMORY_SCOPE_AGENT);
                unsigned int v3 = __hip_atomic_load(sp + 3, __ATOMIC_RELAXED, __HIP_MEMORY_SCOPE_AGENT);
                int byt = (sb * 512 + q * 128 + sj * 16) ^ ((sb & 7) << 4);
                uint4 v; v.x = v0; v.y = v1; v.z = v2; v.w = v3;
                *(uint4*)(hz + byt) = v;
            }
        }
        __syncthreads();

        // ---- MFMA over peer k-slices ----
        #pragma unroll
        for (int qq = 1; qq < 4; ++qq) {
            int q = (p + qq) & 3;
            #pragma unroll
            for (int kk = 0; kk < 2; ++kk) {
                int k0 = (2 * q + kk) * 32 + kg;
                bf16x8_t a0 = *(const bf16x8_t*)(hz + ((mrow * 512 + k0 * 2) ^ ((mrow & 7) << 4)));
                bf16x8_t a1 = *(const bf16x8_t*)(hz + (((mrow + 16) * 512 + k0 * 2) ^ ((mrow & 7) << 4)));
                #pragma unroll
                for (int g = 0; g < 4; ++g) {
                    int n = g * 64 + w * 16 + mrow;
                    bf16x8_t bf = *(const bf16x8_t*)(lds + ((n * 512 + k0 * 2) ^ ((n & 7) << 4)));
                    acc[g][0] = __builtin_amdgcn_mfma_f32_16x16x32_bf16(a0, bf, acc[g][0], 0, 0, 0);
                    acc[g][1] = __builtin_amdgcn_mfma_f32_16x16x32_bf16(a1, bf, acc[g][1], 0, 0, 0);
                }
            }
        }

        // ---- gates fully in-register; write own h -> LDS ----
        #pragma unroll
        for (int mh = 0; mh < 2; ++mh)
            #pragma unroll
            for (int r = 0; r < 4; ++r) {
                int j = mh * 4 + r;
                float iv = sigf(acc[0][mh][r] + bf2f(zxv[0][j]));
                float fv = sigf(acc[1][mh][r] + bf2f(zxv[1][j]));
                float gv = tanhf_fast(acc[2][mh][r] + bf2f(zxv[2][j]));
                float ov = sigf(acc[3][mh][r] + bf2f(zxv[3][j]));
                cst[j] = fv * cst[j] + iv * gv;
                float hh = ov * tanhf_fast(cst[j]);
                int b = mh * 16 + (L >> 4) * 4 + r;
                *(unsigned short*)(hz + ((b * 512 + ug * 2) ^ ((b & 7) << 4))) = f2bf(hh);
            }
        __syncthreads();

        // ---- pack own slice: LDS -> hg (parity tt&1) + Hb ----
        {
            unsigned int* hgp = hgd + (tt & 1) * 4096;
            int byt = (sb * 512 + p * 128 + sj * 16) ^ ((sb & 7) << 4);
            uint4 v = *(const uint4*)(hz + byt);
            unsigned int* dp = hgp + sb * 128 + p * 32 + sj * 4;
            __hip_atomic_store(dp + 0, v.x, __ATOMIC_RELAXED, __HIP_MEMORY_SCOPE_AGENT);
            __hip_atomic_store(dp + 1, v.y, __ATOMIC_RELAXED, __HIP_MEMORY_SCOPE_AGENT);
            __hip_atomic_store(dp + 2, v.z, __ATOMIC_RELAXED, __HIP_MEMORY_SCOPE_AGENT);
            __hip_atomic_store(dp + 3, v.w, __ATOMIC_RELAXED, __HIP_MEMORY_SCOPE_AGENT);
            *(uint4*)(Hb + ((size_t)t * 32 + sb) * 512 + d * 256 + p * 64 + sj * 8) = v;
        }
        __syncthreads();   // compiler drains vmcnt before s_barrier -> stores globally visible

        if (tid == 0)
            __hip_atomic_store(fld + p, (unsigned)(tt + 1), __ATOMIC_RELAXED, __HIP_MEMORY_SCOPE_AGENT);
    }
}

// ---------------- fused attention (bf16 in, bf16 out) ----------------
__global__ __launch_bounds__(256) void attn_fused(
    const unsigned short* __restrict__ qkv, unsigned short* __restrict__ outp)
{
    int s = blockIdx.x & 511;
    int h = blockIdx.x >> 9;
    __shared__ float qs[32][260];
    __shared__ float ks[32][260];
    __shared__ float vs[32][260];
    __shared__ float sc[32][36];
    int tid = threadIdx.x;
    for (int it = 0; it < 32; ++it) {
        const unsigned short* base = qkv + ((size_t)s * 32 + it) * 1536 + h * 256 + tid;
        qs[it][tid] = bf2f(base[0]);
        ks[it][tid] = bf2f(base[512]);
        vs[it][tid] = bf2f(base[1024]);
    }
    __syncthreads();
    int l = tid >> 3, m0 = (tid & 7) * 4;
    float a0 = 0, a1 = 0, a2 = 0, a3 = 0;
    for (int dd = 0; dd < 256; dd += 4) {
        float4 q4 = *(const float4*)&qs[l][dd];
        float4 k0v = *(const float4*)&ks[m0 + 0][dd];
        float4 k1v = *(const float4*)&ks[m0 + 1][dd];
        float4 k2v = *(const float4*)&ks[m0 + 2][dd];
        float4 k3v = *(const float4*)&ks[m0 + 3][dd];
        a0 += q4.x * k0v.x + q4.y * k0v.y + q4.z * k0v.z + q4.w * k0v.w;
        a1 += q4.x * k1v.x + q4.y * k1v.y + q4.z * k1v.z + q4.w * k1v.w;
        a2 += q4.x * k2v.x + q4.y * k2v.y + q4.z * k2v.z + q4.w * k2v.w;
        a3 += q4.x * k3v.x + q4.y * k3v.y + q4.z * k3v.z + q4.w * k3v.w;
    }
    sc[l][m0 + 0] = a0 * 0.0625f;
    sc[l][m0 + 1] = a1 * 0.0625f;
    sc[l][m0 + 2] = a2 * 0.0625f;
    sc[l][m0 + 3] = a3 * 0.0625f;
    __syncthreads();
    if (tid < 32) {
        float mx = -1e30f;
        for (int m = 0; m < 32; ++m) mx = fmaxf(mx, sc[tid][m]);
        float pr[32]; float sm = 0.f;
        for (int m = 0; m < 32; ++m) { pr[m] = __expf(sc[tid][m] - mx); sm += pr[m]; }
        float inv = 1.f / sm;
        for (int m = 0; m < 32; ++m) sc[tid][m] = pr[m] * inv;
    }
    __syncthreads();
    int l2 = tid >> 3, d0 = (tid & 7) * 32;
    float o[32] = {};
    for (int m = 0; m < 32; ++m) {
        float aw = sc[l2][m];
        #pragma unroll
        for (int dd = 0; dd < 32; dd += 4) {
            float4 v4 = *(const float4*)&vs[m][d0 + dd];
            o[dd] += aw * v4.x; o[dd + 1] += aw * v4.y; o[dd + 2] += aw * v4.z; o[dd + 3] += aw * v4.w;
        }
    }
    unsigned short* ob = outp + ((size_t)s * 32 + l2) * 512 + h * 256 + d0;
    #pragma unroll
    for (int dd = 0; dd < 32; dd += 4) {
        ushort4 pv;
        pv.x = f2bf(o[dd]); pv.y = f2bf(o[dd + 1]); pv.z = f2bf(o[dd + 2]); pv.w = f2bf(o[dd + 3]);
        *(ushort4*)(ob + dd) = pv;
    }
}

// ---------------- fc logits (A f32) ----------------
__global__ __launch_bounds__(256) void fc_logits(
    const float* __restrict__ A, const float* __restrict__ fcw, const float* __restrict__ fcb,
    float* __restrict__ outp)
{
    __shared__ float wsm[16][516];
    int tid = threadIdx.x;
    for (int idx = tid; idx < 8192; idx += 256) wsm[idx >> 9][idx & 511] = fcw[idx];
    __syncthreads();
    int r = blockIdx.x * 16 + (tid >> 4);
    int c = tid & 15;
    const float* ar = A + (size_t)r * 512;
    float acc = 0.f;
    for (int k = 0; k < 512; k += 4) {
        float4 a4 = *(const float4*)(ar + k);
        float4 w4 = *(const float4*)&wsm[c][k];
        acc += a4.x * w4.x + a4.y * w4.y + a4.z * w4.z + a4.w * w4.w;
    }
    int s = r >> 5, b = r & 31;
    outp[(size_t)b * 8192 + s * 16 + c] = acc + fcb[c];
}

// ---------------- CRF ----------------
__global__ __launch_bounds__(256) void crf_forward(
    const float* __restrict__ em, const int* __restrict__ labels,
    const float* __restrict__ cs, const float* __restrict__ ce, const float* __restrict__ ct,
    float* __restrict__ res)
{
    int b = blockIdx.x;
    int tid = threadIdx.x;
    int jj = tid >> 4, ii = tid & 15;
    __shared__ float trans[16][17];
    __shared__ float alpha[2][16];
    __shared__ float red[256];
    trans[tid >> 4][tid & 15] = ct[tid & 255];
    const float* emb_ = em + (size_t)b * 8192;
    const int* tg = labels + b * 512;
    float part = 0.f;
    for (int t = tid; t < 512; t += 256) {
        int cur = tg[t];
        part += emb_[t * 16 + cur] + (t == 0 ? cs[cur] : ct[tg[t - 1] * 16 + cur]);
    }
    red[tid] = part;
    if (tid < 16) alpha[0][tid] = cs[tid] + emb_[tid];
    __syncthreads();
    for (int off = 128; off > 0; off >>= 1) {
        if (tid < off) red[tid] += red[tid + off];
        __syncthreads();
    }
    for (int t = 1; t < 512; ++t) {
        int p = t & 1;
        float v = alpha[p ^ 1][ii] + trans[ii][jj];
        float mx = v;
        mx = fmaxf(mx, __shfl_xor(mx, 1));
        mx = fmaxf(mx, __shfl_xor(mx, 2));
        mx = fmaxf(mx, __shfl_xor(mx, 4));
        mx = fmaxf(mx, __shfl_xor(mx, 8));
        float e = __expf(v - mx);
        e += __shfl_xor(e, 1); e += __shfl_xor(e, 2); e += __shfl_xor(e, 4); e += __shfl_xor(e, 8);
        if (ii == 0) alpha[p][jj] = mx + __logf(e) + emb_[t * 16 + jj];
        __syncthreads();
    }
    if (tid == 0) {
        float mx = -1e30f;
        for (int c2 = 0; c2 < 16; ++c2) mx = fmaxf(mx, alpha[1][c2] + ce[c2]);
        float sm = 0.f;
        for (int c2 = 0; c2 < 16; ++c2) sm += __expf(alpha[1][c2] + ce[c2] - mx);
        float logZ = mx + __logf(sm);
        float score = red[0] + ce[tg[511]];
        res[b] = logZ - score;
    }
}

__global__ void crf_final(const float* __restrict__ res, float* __restrict__ nll)
{
    if (threadIdx.x == 0) {
        float s2 = 0.f;
        for (int b = 0; b < 32; ++b) s2 += res[b];
        nll[0] = s2;
    }
}

extern "C" void kernel_launch(void* const* d_in, const int* in_sizes, int n_in,
                              void* d_out, int out_size, void* d_ws, size_t ws_size,
                              hipStream_t stream)
{
    const int* x      = (const int*)d_in[0];
    const int* labels = (const int*)d_in[1];
    const float* emb  = (const float*)d_in[2];
    const float* wih  = (const float*)d_in[3];
    const float* whh  = (const float*)d_in[4];
    const float* bih  = (const float*)d_in[5];
    const float* bhh  = (const float*)d_in[6];
    const float* inw  = (const float*)d_in[7];
    const float* inb  = (const float*)d_in[8];
    const float* opw  = (const float*)d_in[9];
    const float* opb  = (const float*)d_in[10];
    const float* fcw  = (const float*)d_in[11];
    const float* fcb  = (const float*)d_in[12];
    const float* cs   = (const float*)d_in[13];
    const float* ce   = (const float*)d_in[14];
    const float* ct   = (const float*)d_in[15];
    float* out = (float*)d_out;

    // ws layout (MiB offsets), total 128 MiB:
    //  [0,16)   Xb bf16 (embed out)  -> later: hg/flags (64KB, during LSTMs) -> attn-out bf16
    //  [16,32)  H0b bf16             -> res (during CRF)
    //  [32,48)  wihb bf16 (4MiB)     -> H1b bf16 -> opwb bf16 (after qkv gemm)
    //  [48,80)  Zf bf16              -> inwb bf16 (after L1 lstm) -> OPout f32
    //  [80,128) Zb bf16 (32) + qkv bf16 [80,128)
    char* ws = (char*)d_ws;
    const size_t MiB = 1ull << 20;
    unsigned short* Xb     = (unsigned short*)(ws);
    unsigned short* attnO  = (unsigned short*)(ws);
    unsigned int*   hgf    = (unsigned int*)(ws);            // 16384 hg + 8 flags
    unsigned short* H0b    = (unsigned short*)(ws + 16 * MiB);
    float*          res    = (float*)(ws + 16 * MiB);
    unsigned short* H1b    = (unsigned short*)(ws + 32 * MiB);
    unsigned short* wihb   = (unsigned short*)(ws + 32 * MiB);
    unsigned short* opwb   = (unsigned short*)(ws + 32 * MiB);
    unsigned short* Zfb    = (unsigned short*)(ws + 48 * MiB);
    unsigned short* inwb   = (unsigned short*)(ws + 48 * MiB);
    float*          OPout  = (float*)(ws + 48 * MiB);
    unsigned short* Zbb    = (unsigned short*)(ws + 80 * MiB);
    unsigned short* qkv    = (unsigned short*)(ws + 80 * MiB);

    // 1) embedding gather -> Xb bf16
    embed_gather<<<16384, 128, 0, stream>>>(x, emb, Xb);

    // 2) convert all LSTM input weights to bf16 (2,097,152 elems)
    conv_f2b<<<2048, 256, 0, stream>>>(wih, wihb, 2097152);

    // 3) two BiLSTM layers
    for (int l = 0; l < 2; ++l) {
        const unsigned short* Ain = l ? H0b : Xb;
        unsigned short* Ho        = l ? H1b : H0b;
        for (int dd = 0; dd < 2; ++dd) {
            gemm_bf16<1><<<dim3(256, 16), 256, 0, stream>>>(
                Ain, wihb + (size_t)(l * 2 + dd) * 524288,
                bih + (l * 2 + dd) * 1024, bhh + (l * 2 + dd) * 1024,
                dd ? (void*)Zbb : (void*)Zfb, 16384, 1024, 512);
        }
        zero_ws<<<65, 256, 0, stream>>>(hgf, 16392);
        lstm_rec_mfma<<<8, 256, 0, stream>>>(
            Zfb, Zbb, whh + (size_t)l * 524288, hgf, hgf + 16384, Ho);
    }

    // 4) MHA
    conv_f2b<<<768, 256, 0, stream>>>(inw, inwb, 786432);
    gemm_bf16<1><<<dim3(256, 24), 256, 0, stream>>>(H1b, inwb, inb, nullptr, (void*)qkv, 16384, 1536, 512);
    conv_f2b<<<256, 256, 0, stream>>>(opw, opwb, 262144);
    attn_fused<<<1024, 256, 0, stream>>>(qkv, attnO);
    gemm_bf16<0><<<dim3(256, 8), 256, 0, stream>>>(attnO, opwb, opb, nullptr, (void*)OPout, 16384, 512, 512);

    // 5) logits -> d_out
    fc_logits<<<1024, 256, 0, stream>>>(OPout, fcw, fcb, out);

    // 6) CRF
    crf_forward<<<32, 256, 0, stream>>>(out, labels, cs, ce, ct, res);
    crf_final<<<1, 64, 0, stream>>>(res, out + 262144);

    (void)in_sizes; (void)n_in; (void)out_size; (void)ws_size;
}